// Round 1
// baseline (20.515 us; speedup 1.0000x reference)
//
#include <hip/hip_runtime.h>
#include <math.h>

namespace {

constexpr int IN_C = 3, OUT_C = 8, QDEPTH = 2, WIRES = 4, DIM = 16;
constexpr int H = 128, W = 128;

// CNOT with compile-time control/target wires (wire 0 = MSB of the 4-bit index)
template <int C, int T>
__device__ __forceinline__ void cnot(float* sr, float* si) {
    constexpr int cm = 1 << (3 - C);
    constexpr int tm = 1 << (3 - T);
#pragma unroll
    for (int n = 0; n < DIM; ++n) {
        if ((n & cm) != 0 && (n & tm) == 0) {
            const int n1 = n | tm;
            float tr = sr[n]; sr[n] = sr[n1]; sr[n1] = tr;
            float ti = si[n]; si[n] = si[n1]; si[n1] = ti;
        }
    }
}

__global__ __launch_bounds__(256) void qconv_kernel(const float* __restrict__ x,
                                                    const float* __restrict__ w,
                                                    float* __restrict__ out) {
    // --- precompute the 24 Rot matrices (thread-uniform) into LDS ---
    __shared__ float mats[IN_C * QDEPTH * WIRES * 8];
    const int t = threadIdx.x;
    if (t < IN_C * QDEPTH * WIRES) {
        const float phi = w[t * 3 + 0], th = w[t * 3 + 1], om = w[t * 3 + 2];
        float st, ct; sincosf(0.5f * th, &st, &ct);
        float sa, ca; sincosf(0.5f * (phi + om), &sa, &ca);
        float sb, cb; sincosf(0.5f * (phi - om), &sb, &cb);
        float* m = &mats[t * 8];
        m[0] = ct * ca;  m[1] = -ct * sa;   // m00 = e^{-i(phi+om)/2} cos(th/2)
        m[2] = -st * cb; m[3] = -st * sb;   // m01 = -e^{+i(phi-om)/2} sin(th/2)
        m[4] = st * cb;  m[5] = -st * sb;   // m10 = e^{-i(phi-om)/2} sin(th/2)
        m[6] = ct * ca;  m[7] = ct * sa;    // m11 = e^{+i(phi+om)/2} cos(th/2)
    }
    __syncthreads();

    const int tid = blockIdx.x * blockDim.x + t;   // b*16384 + i*128 + j
    const int b = tid >> 14;
    const int i = (tid >> 7) & 127;
    const int j = tid & 127;

    // --- 16-dim complex statevector in registers ---
    float sr[DIM], si[DIM];
#pragma unroll
    for (int n = 0; n < DIM; ++n) { sr[n] = 0.f; si[n] = 0.f; }
    sr[0] = 1.f;

    for (int ic = 0; ic < IN_C; ++ic) {
        // p = (patch + 0.01)^2 ; normalization is scale-invariant in the cascade -> skipped
        float p[DIM];
        const float* xc = x + ((size_t)(b * IN_C + ic) << 14);
#pragma unroll
        for (int di = 0; di < 3; ++di) {
#pragma unroll
            for (int dj = 0; dj < 3; ++dj) {
                const int y = i + di - 1, z = j + dj - 1;
                float v = 0.f;
                if (y >= 0 && y < H && z >= 0 && z < W) v = xc[(y << 7) + z];
                v += 0.01f;
                p[di * 3 + dj] = v * v;
            }
        }
#pragma unroll
        for (int n = 9; n < DIM; ++n) p[n] = 1e-4f;

        // --- Mottonen RY cascade: sin(half)=sqrt(ratio), cos(half)=sqrt(1-ratio) ---
#pragma unroll
        for (int q = 0; q < WIRES; ++q) {
            const int half = 1 << (3 - q);
            const int blk = half << 1;
#pragma unroll
            for (int g = 0; g < (1 << q); ++g) {
                float num = 0.f, den = 0.f;
#pragma unroll
                for (int jj = 0; jj < half; ++jj) {
                    den += p[g * blk + jj];
                    num += p[g * blk + half + jj];
                }
                den += num;
                float ratio = (den > 1e-12f) ? (num / den) : 0.f;
                ratio = fminf(fmaxf(ratio, 0.f), 1.f);
                const float s = sqrtf(ratio);
                const float c = sqrtf(1.f - ratio);
#pragma unroll
                for (int jj = 0; jj < half; ++jj) {
                    const int n0 = g * blk + jj, n1 = n0 + half;
                    const float r0 = sr[n0], i0 = si[n0];
                    const float r1 = sr[n1], i1 = si[n1];
                    sr[n0] = c * r0 - s * r1; si[n0] = c * i0 - s * i1;
                    sr[n1] = s * r0 + c * r1; si[n1] = s * i0 + c * i1;
                }
            }
        }

        // --- StronglyEntanglingLayers ---
#pragma unroll
        for (int l = 0; l < QDEPTH; ++l) {
#pragma unroll
            for (int q = 0; q < WIRES; ++q) {
                const float* m = &mats[((ic * QDEPTH + l) * WIRES + q) * 8];
                const float m00r = m[0], m00i = m[1], m01r = m[2], m01i = m[3];
                const float m10r = m[4], m10i = m[5], m11r = m[6], m11i = m[7];
                const int mask = 1 << (3 - q);
#pragma unroll
                for (int n = 0; n < DIM; ++n) {
                    if ((n & mask) == 0) {
                        const int n1 = n | mask;
                        const float r0 = sr[n], i0 = si[n];
                        const float r1 = sr[n1], i1 = si[n1];
                        sr[n]  = m00r * r0 - m00i * i0 + m01r * r1 - m01i * i1;
                        si[n]  = m00r * i0 + m00i * r0 + m01r * i1 + m01i * r1;
                        sr[n1] = m10r * r0 - m10i * i0 + m11r * r1 - m11i * i1;
                        si[n1] = m10r * i0 + m10i * r0 + m11r * i1 + m11i * r1;
                    }
                }
            }
            if (l == 0) {  // r = 1
                cnot<0, 1>(sr, si); cnot<1, 2>(sr, si);
                cnot<2, 3>(sr, si); cnot<3, 0>(sr, si);
            } else {       // r = 2
                cnot<0, 2>(sr, si); cnot<1, 3>(sr, si);
                cnot<2, 0>(sr, si); cnot<3, 1>(sr, si);
            }
        }
    }

    // --- output: clip(|amp|^2 * 8, 0, 1) for basis states 0..7 ---
    float* ob = out + ((size_t)b << 17) + (i << 7) + j;  // (b, oc, i, j) of (4,8,128,128)
#pragma unroll
    for (int oc = 0; oc < OUT_C; ++oc) {
        const float pr = (sr[oc] * sr[oc] + si[oc] * si[oc]) * 8.f;
        ob[(size_t)oc << 14] = fminf(fmaxf(pr, 0.f), 1.f);
    }
}

}  // namespace

extern "C" void kernel_launch(void* const* d_in, const int* in_sizes, int n_in,
                              void* d_out, int out_size, void* d_ws, size_t ws_size,
                              hipStream_t stream) {
    const float* x = (const float*)d_in[0];        // (4,3,128,128) f32
    const float* w = (const float*)d_in[1];        // (3,2,4,3) f32
    float* out = (float*)d_out;                    // (4,8,128,128) f32
    const int total = 4 * 128 * 128;               // one thread per output pixel
    qconv_kernel<<<total / 256, 256, 0, stream>>>(x, w, out);
}

// Round 2
// 15.380 us; speedup vs baseline: 1.3339x; 1.3339x over previous
//
#include <hip/hip_runtime.h>
#include <math.h>

namespace {

typedef __attribute__((ext_vector_type(2))) float f32x2;

constexpr int IN_C = 3, OUT_C = 8, QDEPTH = 2, WIRES = 4, DIM = 16;
constexpr int H = 128, W = 128;

// ---- packed fp32 helpers (VOP3P) ----
__device__ __forceinline__ f32x2 pk_mul(f32x2 a, f32x2 b) {
    f32x2 d;
    asm("v_pk_mul_f32 %0, %1, %2" : "=v"(d) : "v"(a), "v"(b));
    return d;
}
__device__ __forceinline__ f32x2 pk_fma(f32x2 a, f32x2 b, f32x2 c) {
    f32x2 d;
    asm("v_pk_fma_f32 %0, %1, %2, %3" : "=v"(d) : "v"(a), "v"(b), "v"(c));
    return d;
}
// d = a * (-b.y, b.x) + c   == c + a*(i*b)  (complex-imag part, swap+neg folded)
__device__ __forceinline__ f32x2 pk_fma_swapneg(f32x2 a, f32x2 b, f32x2 c) {
    f32x2 d;
    asm("v_pk_fma_f32 %0, %1, %2, %3 op_sel:[0,1,0] op_sel_hi:[1,0,1] neg_lo:[0,1,0]"
        : "=v"(d) : "v"(a), "v"(b), "v"(c));
    return d;
}
// d = -(a*b) + c
__device__ __forceinline__ f32x2 pk_fnma(f32x2 a, f32x2 b, f32x2 c) {
    f32x2 d;
    asm("v_pk_fma_f32 %0, %1, %2, %3 neg_lo:[1,0,0] neg_hi:[1,0,0]"
        : "=v"(d) : "v"(a), "v"(b), "v"(c));
    return d;
}

// RY butterfly with explicit (c,s): out0 = c*v0 - s*v1 ; out1 = s*v0 + c*v1
template <int BASE, int HALF>
__device__ __forceinline__ void ry_cs(f32x2* st, float c, float s) {
    const f32x2 c2 = {c, c}, s2 = {s, s};
#pragma unroll
    for (int jj = 0; jj < HALF; ++jj) {
        const f32x2 v0 = st[BASE + jj], v1 = st[BASE + HALF + jj];
        st[BASE + jj]        = pk_fnma(s2, v1, pk_mul(c2, v0));
        st[BASE + HALF + jj] = pk_fma(s2, v0, pk_mul(c2, v1));
    }
}

// RY butterfly from (lo,hi) probability sums: s=sqrt(hi/(lo+hi)), c=sqrt(lo/(lo+hi))
template <int BASE, int HALF>
__device__ __forceinline__ void ry(f32x2* st, float lo, float hi) {
    const float rs = __builtin_amdgcn_rsqf(lo + hi);
    const float s = __builtin_amdgcn_sqrtf(hi) * rs;
    const float c = __builtin_amdgcn_sqrtf(lo) * rs;
    ry_cs<BASE, HALF>(st, c, s);
}

// Rot (2x2 complex unitary) on wire with mask MASK; m = 8 broadcast pairs in LDS
template <int MASK>
__device__ __forceinline__ void rot(f32x2* st, const f32x2* __restrict__ m) {
    const f32x2 m00r = m[0], m00i = m[1], m01r = m[2], m01i = m[3];
    const f32x2 m10r = m[4], m10i = m[5], m11r = m[6], m11i = m[7];
#pragma unroll
    for (int n = 0; n < DIM; ++n) {
        if ((n & MASK) == 0) {
            const int n1 = n | MASK;
            const f32x2 v0 = st[n], v1 = st[n1];
            f32x2 o0 = pk_mul(m00r, v0);
            o0 = pk_fma_swapneg(m00i, v0, o0);
            o0 = pk_fma(m01r, v1, o0);
            o0 = pk_fma_swapneg(m01i, v1, o0);
            f32x2 o1 = pk_mul(m10r, v0);
            o1 = pk_fma_swapneg(m10i, v0, o1);
            o1 = pk_fma(m11r, v1, o1);
            o1 = pk_fma_swapneg(m11i, v1, o1);
            st[n] = o0; st[n1] = o1;
        }
    }
}

template <int C, int T>
__device__ __forceinline__ void cnot(f32x2* st) {
    constexpr int cm = 1 << (3 - C);
    constexpr int tm = 1 << (3 - T);
#pragma unroll
    for (int n = 0; n < DIM; ++n) {
        if ((n & cm) != 0 && (n & tm) == 0) {
            const int n1 = n | tm;
            const f32x2 tmp = st[n]; st[n] = st[n1]; st[n1] = tmp;
        }
    }
}

__global__ __launch_bounds__(256) void qconv_kernel(const float* __restrict__ x,
                                                    const float* __restrict__ w,
                                                    float* __restrict__ out) {
    // 24 Rot matrices as pre-broadcast f32x2 pairs in LDS
    __shared__ f32x2 mats[IN_C * QDEPTH * WIRES * 8];
    const int t = threadIdx.x;
    if (t < IN_C * QDEPTH * WIRES) {
        const float phi = w[t * 3 + 0], th = w[t * 3 + 1], om = w[t * 3 + 2];
        float sth, cth; sincosf(0.5f * th, &sth, &cth);
        float sa, ca;   sincosf(0.5f * (phi + om), &sa, &ca);
        float sb, cb;   sincosf(0.5f * (phi - om), &sb, &cb);
        f32x2* m = &mats[t * 8];
        const float m00r =  cth * ca, m00i = -cth * sa;
        const float m01r = -sth * cb, m01i = -sth * sb;
        const float m10r =  sth * cb, m10i = -sth * sb;
        const float m11r =  cth * ca, m11i =  cth * sa;
        m[0] = {m00r, m00r}; m[1] = {m00i, m00i};
        m[2] = {m01r, m01r}; m[3] = {m01i, m01i};
        m[4] = {m10r, m10r}; m[5] = {m10i, m10i};
        m[6] = {m11r, m11r}; m[7] = {m11i, m11i};
    }
    __syncthreads();

    const int tid = blockIdx.x * blockDim.x + t;   // b*16384 + i*128 + j
    const int b = tid >> 14;
    const int i = (tid >> 7) & 127;
    const int j = tid & 127;

    f32x2 st[DIM];
#pragma unroll
    for (int n = 0; n < DIM; ++n) st[n] = {0.f, 0.f};
    st[0].x = 1.f;

    constexpr float RH = 0.70710678118654752f;  // sqrt(1/2)

    for (int ic = 0; ic < IN_C; ++ic) {
        // p[k] = (patch_k + 0.01)^2 for k<9 ; 1e-4 for k>=9 (normalization is
        // scale-invariant through the ratio -> skipped entirely)
        float p[9];
        const float* xc = x + ((size_t)(b * IN_C + ic) << 14);
#pragma unroll
        for (int di = 0; di < 3; ++di) {
#pragma unroll
            for (int dj = 0; dj < 3; ++dj) {
                const int y = i + di - 1, z = j + dj - 1;
                float v = 0.f;
                if ((unsigned)y < (unsigned)H && (unsigned)z < (unsigned)W)
                    v = xc[(y << 7) + z];
                v += 0.01f;
                p[di * 3 + dj] = v * v;
            }
        }
        // binary tree of partial sums (constants beyond index 8 folded)
        const float t10 = p[0] + p[1], t11 = p[2] + p[3];
        const float t12 = p[4] + p[5], t13 = p[6] + p[7];
        const float t14 = p[8] + 1e-4f;            // t15,t16,t17 = 2e-4 (const)
        const float t20 = t10 + t11, t21 = t12 + t13;
        const float t22 = t14 + 2e-4f;             // t23 = 4e-4 (const)
        const float t30 = t20 + t21;
        const float t31 = t22 + 4e-4f;

        // --- Mottonen RY cascade (wire 0 = MSB) ---
        ry<0, 8>(st, t30, t31);                                  // q=0
        ry<0, 4>(st, t20, t21);  ry<8, 4>(st, t22, 4e-4f);       // q=1
        ry<0, 2>(st, t10, t11);  ry<4, 2>(st, t12, t13);         // q=2
        ry<8, 2>(st, t14, 2e-4f); ry_cs<12, 2>(st, RH, RH);
        ry<0, 1>(st, p[0], p[1]); ry<2, 1>(st, p[2], p[3]);      // q=3
        ry<4, 1>(st, p[4], p[5]); ry<6, 1>(st, p[6], p[7]);
        ry<8, 1>(st, p[8], 1e-4f);
        ry_cs<10, 1>(st, RH, RH); ry_cs<12, 1>(st, RH, RH); ry_cs<14, 1>(st, RH, RH);

        // --- StronglyEntanglingLayers ---
        const f32x2* mb = &mats[ic * QDEPTH * WIRES * 8];
        // layer 0 (range 1)
        rot<8>(st, mb + 0);  rot<4>(st, mb + 8);
        rot<2>(st, mb + 16); rot<1>(st, mb + 24);
        cnot<0, 1>(st); cnot<1, 2>(st); cnot<2, 3>(st); cnot<3, 0>(st);
        // layer 1 (range 2)
        rot<8>(st, mb + 32); rot<4>(st, mb + 40);
        rot<2>(st, mb + 48); rot<1>(st, mb + 56);
        cnot<0, 2>(st); cnot<1, 3>(st); cnot<2, 0>(st); cnot<3, 1>(st);
    }

    // --- output: clip(|amp|^2 * 8, 0, 1), basis states 0..7 ---
    float* ob = out + ((size_t)b << 17) + (i << 7) + j;  // (4,8,128,128)
#pragma unroll
    for (int oc = 0; oc < OUT_C; ++oc) {
        const float pr = (st[oc].x * st[oc].x + st[oc].y * st[oc].y) * 8.f;
        ob[(size_t)oc << 14] = fminf(pr, 1.f);
    }
}

}  // namespace

extern "C" void kernel_launch(void* const* d_in, const int* in_sizes, int n_in,
                              void* d_out, int out_size, void* d_ws, size_t ws_size,
                              hipStream_t stream) {
    const float* x = (const float*)d_in[0];        // (4,3,128,128) f32
    const float* w = (const float*)d_in[1];        // (3,2,4,3) f32
    float* out = (float*)d_out;                    // (4,8,128,128) f32
    const int total = 4 * 128 * 128;
    qconv_kernel<<<total / 256, 256, 0, stream>>>(x, w, out);
}

// Round 3
// 15.057 us; speedup vs baseline: 1.3625x; 1.0215x over previous
//
#include <hip/hip_runtime.h>
#include <math.h>

namespace {

typedef __attribute__((ext_vector_type(2))) float f32x2;

constexpr int H = 128, W = 128;

// ---------- packed fp32 (VOP3P) with op_sel scalar-broadcast ----------
// d = a.x * b
__device__ __forceinline__ f32x2 pk_mul_x(f32x2 a, f32x2 b) {
    f32x2 d; asm("v_pk_mul_f32 %0, %1, %2 op_sel:[0,0] op_sel_hi:[0,1]"
                 : "=v"(d) : "v"(a), "v"(b)); return d;
}
// d = c + a.x * b
__device__ __forceinline__ f32x2 pk_fma_x(f32x2 a, f32x2 b, f32x2 c) {
    f32x2 d; asm("v_pk_fma_f32 %0, %1, %2, %3 op_sel:[0,0,0] op_sel_hi:[0,1,1]"
                 : "=v"(d) : "v"(a), "v"(b), "v"(c)); return d;
}
// d = c + a.y * b
__device__ __forceinline__ f32x2 pk_fma_y(f32x2 a, f32x2 b, f32x2 c) {
    f32x2 d; asm("v_pk_fma_f32 %0, %1, %2, %3 op_sel:[1,0,0] op_sel_hi:[1,1,1]"
                 : "=v"(d) : "v"(a), "v"(b), "v"(c)); return d;
}
// d = c - a.y * b
__device__ __forceinline__ f32x2 pk_fnma_y(f32x2 a, f32x2 b, f32x2 c) {
    f32x2 d; asm("v_pk_fma_f32 %0, %1, %2, %3 op_sel:[1,0,0] op_sel_hi:[1,1,1] neg_lo:[1,0,0] neg_hi:[1,0,0]"
                 : "=v"(d) : "v"(a), "v"(b), "v"(c)); return d;
}
// d = c + a.y * (i*b):  lo = c.x - a.y*b.y ; hi = c.y + a.y*b.x
__device__ __forceinline__ f32x2 pk_fma_im(f32x2 a, f32x2 b, f32x2 c) {
    f32x2 d; asm("v_pk_fma_f32 %0, %1, %2, %3 op_sel:[1,1,0] op_sel_hi:[1,0,1] neg_lo:[0,1,0]"
                 : "=v"(d) : "v"(a), "v"(b), "v"(c)); return d;
}
// complex d = m*v / d = acc + m*v, m = {re, im} packed in one f32x2
__device__ __forceinline__ f32x2 cmul(f32x2 m, f32x2 v) { return pk_fma_im(m, v, pk_mul_x(m, v)); }
__device__ __forceinline__ f32x2 cfma(f32x2 m, f32x2 v, f32x2 a) { return pk_fma_im(m, v, pk_fma_x(m, v, a)); }

// ---------- partner-lane exchange (lanes 2m <-> 2m+1), DPP quad_perm [1,0,3,2] ----------
__device__ __forceinline__ float dpp1(float v) {
    return __int_as_float(__builtin_amdgcn_update_dpp(0, __float_as_int(v), 0xB1, 0xF, 0xF, true));
}
__device__ __forceinline__ f32x2 xpair(f32x2 v) { f32x2 r; r.x = dpp1(v.x); r.y = dpp1(v.y); return r; }

// (c,s) = (sqrt(lo/(lo+hi)), sqrt(hi/(lo+hi)))
__device__ __forceinline__ f32x2 make_cs(float lo, float hi) {
    const float rs = __builtin_amdgcn_rsqf(lo + hi);
    f32x2 cs; cs.x = __builtin_amdgcn_sqrtf(lo) * rs; cs.y = __builtin_amdgcn_sqrtf(hi) * rs;
    return cs;
}

#define RYP(i0, i1) { const f32x2 v0 = st[i0], v1 = st[i1];                         \
    st[i0] = pk_fnma_y(cs, v1, pk_mul_x(cs, v0));                                    \
    st[i1] = pk_fma_y(cs, v0, pk_mul_x(cs, v1)); }

#define ROTP(i0, i1) { const f32x2 v0 = st[i0], v1 = st[i1];                        \
    st[i0] = cfma(M01, v1, cmul(M00, v0));                                           \
    st[i1] = cfma(M11, v1, cmul(M10, v0)); }

#define SWAPV(a, b) { const f32x2 _t = (a); (a) = (b); (b) = _t; }

// u-conditional local permute k <-> k^M (CNOT with control on the split wire)
template <int M>
__device__ __forceinline__ void cswap_local(f32x2* st, bool hi) {
#pragma unroll
    for (int k = 0; k < 8; ++k) {
        if ((k & M) == 0) {
            const f32x2 A = st[k], B = st[k | M];
            st[k] = hi ? B : A;
            st[k | M] = hi ? A : B;
        }
    }
}
// cross-thread exchange of slots with (k & M) != 0 (CNOT with target on the split wire)
template <int M>
__device__ __forceinline__ void cx0(f32x2* st) {
#pragma unroll
    for (int k = 0; k < 8; ++k)
        if (k & M) st[k] = xpair(st[k]);
}

__device__ __forceinline__ void load9(float* a, const float* __restrict__ xc, int i, int j) {
#pragma unroll
    for (int di = 0; di < 3; ++di) {
#pragma unroll
        for (int dj = 0; dj < 3; ++dj) {
            const int y = i + di - 1, z = j + dj - 1;
            float v = 0.f;
            if ((unsigned)y < (unsigned)H && (unsigned)z < (unsigned)W) v = xc[(y << 7) + z];
            a[di * 3 + dj] = v + 0.01f;
        }
    }
}

// Mottonen cascade for a general incoming state, split form (each lane: 8 amps)
__device__ __forceinline__ void cascade(f32x2* st, const float* a, bool hi) {
    float p[9];
#pragma unroll
    for (int k = 0; k < 9; ++k) p[k] = a[k] * a[k];
    const float t10 = p[0] + p[1], t11 = p[2] + p[3], t12 = p[4] + p[5], t13 = p[6] + p[7];
    const float t14 = p[8] + 1e-4f;
    const float t20 = t10 + t11, t21 = t12 + t13, t22 = t14 + 2e-4f;
    const float t30 = t20 + t21, t31 = t22 + 4e-4f;

    // q0: cross pairs (n, n+8). A: c*v - s*w ; B: c*v + s*w  (w = partner's slot)
    {
        f32x2 cs0 = make_cs(t30, t31);
        cs0.y = hi ? cs0.y : -cs0.y;
#pragma unroll
        for (int k = 0; k < 8; ++k) {
            const f32x2 w = xpair(st[k]);
            st[k] = pk_fma_y(cs0, w, pk_mul_x(cs0, st[k]));
        }
    }
    // q1 (local mask 4): A group (t20,t21); B group (t22, 4e-4)
    { const f32x2 cs = make_cs(hi ? t22 : t20, hi ? 4e-4f : t21);
      RYP(0, 4) RYP(1, 5) RYP(2, 6) RYP(3, 7) }
    // q2 (mask 2)
    { const f32x2 cs = make_cs(hi ? t14 : t10, hi ? 2e-4f : t11); RYP(0, 2) RYP(1, 3) }
    { const f32x2 cs = make_cs(hi ? 1.f : t12, hi ? 1.f : t13);   RYP(4, 6) RYP(5, 7) }
    // q3 (mask 1)
    { const f32x2 cs = make_cs(hi ? p[8] : p[0], hi ? 1e-4f : p[1]); RYP(0, 1) }
    { const f32x2 cs = make_cs(hi ? 1.f : p[2], hi ? 1.f : p[3]);    RYP(2, 3) }
    { const f32x2 cs = make_cs(hi ? 1.f : p[4], hi ? 1.f : p[5]);    RYP(4, 5) }
    { const f32x2 cs = make_cs(hi ? 1.f : p[6], hi ? 1.f : p[7]);    RYP(6, 7) }
}

// One rot layer: wire0 = cross (role-split matrix rows via LDS offset), wires 1-3 local
__device__ __forceinline__ void rot_layer(f32x2* st, const f32x2* __restrict__ mats,
                                          int base, int u) {
    {   // wire 0: A: o = m00*v + m01*w ; B: o = m11*v + m10*w
        const f32x2 ma = mats[base + 3 * u], mb = mats[base + 1 + u];
#pragma unroll
        for (int k = 0; k < 8; ++k) {
            const f32x2 w = xpair(st[k]);
            st[k] = cfma(mb, w, cmul(ma, st[k]));
        }
    }
    {   // wire 1 (mask 4)
        const f32x2 M00 = mats[base + 4], M01 = mats[base + 5],
                    M10 = mats[base + 6], M11 = mats[base + 7];
        ROTP(0, 4) ROTP(1, 5) ROTP(2, 6) ROTP(3, 7)
    }
    {   // wire 2 (mask 2)
        const f32x2 M00 = mats[base + 8], M01 = mats[base + 9],
                    M10 = mats[base + 10], M11 = mats[base + 11];
        ROTP(0, 2) ROTP(1, 3) ROTP(4, 6) ROTP(5, 7)
    }
    {   // wire 3 (mask 1)
        const f32x2 M00 = mats[base + 12], M01 = mats[base + 13],
                    M10 = mats[base + 14], M11 = mats[base + 15];
        ROTP(0, 1) ROTP(2, 3) ROTP(4, 5) ROTP(6, 7)
    }
}

__device__ __forceinline__ void entangle(f32x2* st, const f32x2* __restrict__ mats,
                                         int ic, int u, bool hi) {
    rot_layer(st, mats, (ic * 2 + 0) * 16, u);
    // layer-0 CNOTs (range 1): (0,1) (1,2) (2,3) (3,0)
    cswap_local<4>(st, hi);
    SWAPV(st[4], st[6]) SWAPV(st[5], st[7])
    SWAPV(st[2], st[3]) SWAPV(st[6], st[7])
    cx0<1>(st);
    rot_layer(st, mats, (ic * 2 + 1) * 16, u);
    // layer-1 CNOTs (range 2): (0,2) (1,3) (2,0) (3,1)
    cswap_local<2>(st, hi);
    SWAPV(st[4], st[5]) SWAPV(st[6], st[7])
    cx0<2>(st);
    SWAPV(st[1], st[5]) SWAPV(st[3], st[7])
}

__global__ __launch_bounds__(256) void qconv_kernel(const float* __restrict__ x,
                                                    const float* __restrict__ w,
                                                    float* __restrict__ out) {
    // 24 Rot matrices, packed {re,im}: [m00, m01, m10, m11] per matrix (32 B)
    __shared__ f32x2 mats[24 * 4];
    const int t = threadIdx.x;
    if (t < 24) {
        const float phi = w[t * 3 + 0], th = w[t * 3 + 1], om = w[t * 3 + 2];
        float sth, cth; sincosf(0.5f * th, &sth, &cth);
        float sa, ca;   sincosf(0.5f * (phi + om), &sa, &ca);
        float sb, cb;   sincosf(0.5f * (phi - om), &sb, &cb);
        f32x2* m = &mats[t * 4];
        m[0] = { cth * ca, -cth * sa};   // m00
        m[1] = {-sth * cb, -sth * sb};   // m01
        m[2] = { sth * cb, -sth * sb};   // m10
        m[3] = { cth * ca,  cth * sa};   // m11
    }
    __syncthreads();

    const int gid = blockIdx.x * 256 + t;      // 2 lanes per pixel
    const int u = gid & 1;
    const bool hi = (u != 0);
    const int pix = gid >> 1;                  // b*16384 + i*128 + j
    const int b = pix >> 14, rem = pix & 16383, i = rem >> 7, j = rem & 127;
    const float* xb = x + ((size_t)(b * 3) << 14);

    f32x2 st[8];

    // ---- channel 0: Mottonen on |0> == direct normalization ----
    float a0[9]; load9(a0, xb, i, j);
    {
        float s2 = 0.f;
#pragma unroll
        for (int k = 0; k < 9; ++k) s2 += a0[k] * a0[k];
        const float rs = __builtin_amdgcn_rsqf(s2 + 7e-4f);
#pragma unroll
        for (int k = 0; k < 8; ++k) {
            const float ak = hi ? (k == 0 ? a0[8] : 0.01f) : a0[k];
            st[k].x = ak * rs; st[k].y = 0.f;
        }
    }
    float a1[9]; load9(a1, xb + (1 << 14), i, j);   // prefetch ch1
    entangle(st, mats, 0, u, hi);

    cascade(st, a1, hi);
    float a2[9]; load9(a2, xb + (2 << 14), i, j);   // prefetch ch2
    entangle(st, mats, 1, u, hi);

    cascade(st, a2, hi);
    entangle(st, mats, 2, u, hi);

    // ---- output: lane A (u==0) holds basis states 0..7 ----
    if (!hi) {
        float* ob = out + ((size_t)b << 17) + (i << 7) + j;
#pragma unroll
        for (int k = 0; k < 8; ++k) {
            const float pr = (st[k].x * st[k].x + st[k].y * st[k].y) * 8.f;
            ob[(size_t)k << 14] = fminf(pr, 1.f);
        }
    }
}

}  // namespace

extern "C" void kernel_launch(void* const* d_in, const int* in_sizes, int n_in,
                              void* d_out, int out_size, void* d_ws, size_t ws_size,
                              hipStream_t stream) {
    const float* x = (const float*)d_in[0];        // (4,3,128,128) f32
    const float* w = (const float*)d_in[1];        // (3,2,4,3) f32
    float* out = (float*)d_out;                    // (4,8,128,128) f32
    const int total = 4 * 128 * 128 * 2;           // 2 threads per pixel
    qconv_kernel<<<total / 256, 256, 0, stream>>>(x, w, out);
}